// Round 8
// baseline (339.359 us; speedup 1.0000x reference)
//
#include <hip/hip_runtime.h>
#include <cstdint>

#define B_SZ 8192
#define IN_SZ 1024
#define H_SZ 1024

typedef unsigned short u16;
typedef __bf16 bf16_t;
typedef bf16_t bf16x8 __attribute__((ext_vector_type(8)));
typedef float floatx4 __attribute__((ext_vector_type(4)));

__device__ __forceinline__ u16 f2bf(float f) {
    unsigned int u = __float_as_uint(f);
    u += 0x7fffu + ((u >> 16) & 1u);   // RNE
    return (u16)(u >> 16);
}

__device__ __forceinline__ ushort4 cvt4(float4 v) {
    ushort4 o;
    o.x = f2bf(v.x); o.y = f2bf(v.y); o.z = f2bf(v.z); o.w = f2bf(v.w);
    return o;
}

// async global->LDS, 16B per lane; LDS dest = wave-uniform base + lane*16
__device__ __forceinline__ void g2l16(const u16* g, u16* l) {
    __builtin_amdgcn_global_load_lds(
        (__attribute__((address_space(1))) void*)(uintptr_t)g,
        (__attribute__((address_space(3))) void*)(uint32_t)(uintptr_t)l,
        16, 0, 0);
}

__device__ __forceinline__ void sbar0() { __builtin_amdgcn_sched_barrier(0); }
__device__ __forceinline__ void wait_vm2() {   // all but newest 2 VMEM complete
    asm volatile("s_waitcnt vmcnt(2)" ::: "memory");
}
__device__ __forceinline__ void wait_vm0() {
    asm volatile("s_waitcnt vmcnt(0)" ::: "memory");
}

// ---------------- fused fp32 -> bf16 conversion into K-concat layouts -----------
// Acat[8192][2048] = [bf16(input) | bf16(hidden)]
// Brz [2048][2048] = [[Wir|Whr],[Wiz|Whz]];  Bh [1024][2048] = [Wih|Whh]
__global__ __launch_bounds__(256) void cvt_all(
    const float* __restrict__ x, const float* __restrict__ h,
    const float* __restrict__ Wir, const float* __restrict__ Whr,
    const float* __restrict__ Wiz, const float* __restrict__ Whz,
    const float* __restrict__ Wih, const float* __restrict__ Whh,
    u16* __restrict__ Acat, u16* __restrict__ Brz, u16* __restrict__ Bh) {
    const int b = blockIdx.x;
    const int t = threadIdx.x;
    if (b < 8192) {
        float4 v = ((const float4*)(x + (size_t)b * 1024))[t];
        ((ushort4*)(Acat + (size_t)b * 2048))[t] = cvt4(v);
    } else if (b < 16384) {
        const int m = b - 8192;
        float4 v = ((const float4*)(h + (size_t)m * 1024))[t];
        ((ushort4*)(Acat + (size_t)m * 2048 + 1024))[t] = cvt4(v);
    } else {
        const int wb = b - 16384;   // 0..6143
        const int w = wb >> 10;
        const int n = wb & 1023;
        const float* src;
        u16* dst;
        switch (w) {
            case 0: src = Wir; dst = Brz + (size_t)n * 2048;               break;
            case 1: src = Whr; dst = Brz + (size_t)n * 2048 + 1024;        break;
            case 2: src = Wiz; dst = Brz + (size_t)(n + 1024) * 2048;      break;
            case 3: src = Whz; dst = Brz + (size_t)(n + 1024) * 2048 + 1024; break;
            case 4: src = Wih; dst = Bh + (size_t)n * 2048;                break;
            default: src = Whh; dst = Bh + (size_t)n * 2048 + 1024;        break;
        }
        float4 v = ((const float4*)(src + (size_t)n * 1024))[t];
        ((ushort4*)dst)[t] = cvt4(v);
    }
}

// ---------------- K=2048 NT GEMM: ring-4 A-DMA + reg-staged B (T14) -------------
// r5 base (best GEMM this session; verified invariants), with:
//  * A via global_load_lds ring-4 (prefetch distance 3, counted vmcnt)
//  * B via global_load->regs (issued for tile t+3 at tile t's start; HBM latency
//    hides under compute) -> ds_write_b128 after a counted vmcnt(2) at tile close.
//    The same vmcnt(2) forces A(t+1)/A(t+2) complete (in-order vmcnt queue):
//    per-tile issue order [B pend (BG), A dma (2)] -> wait "all but newest 2".
//    Halves the per-CU gload_lds instruction count (H: DMA path ~128cyc/instr).
//  * constexpr strides, per-thread base pointers hoisted (no per-tile 64b MUL).
// LDS layout (T2, 0 conflicts measured r5): 256B super-rows pairing rows r>>1,
// 16B-unit = ((r&1)*4+kslot) ^ ((r>>1)&7); source coords inverse-permuted, LDS
// linear; ds_read and ds_write use the same mapping (rule #21 both-sides).
// MODE 0 (r+z, N=2048): col<1024 -> out_rh=bf16(sigmoid(C+b)*hidden);
//                       col>=1024 -> out_zf[.,c-1024]=sigmoid(C+b)
// MODE 2 (h~, N=1024): ht=tanh(C+b); out_f = z*hidden + (1-z)*ht
template <int MODE, int BN, int LWN, int SA0, int SA1>
__device__ __forceinline__ void gemm_core(
    const u16* __restrict__ A0, const u16* __restrict__ A1,
    const u16* __restrict__ Bw,
    const float* __restrict__ bx0, const float* __restrict__ bh0,
    const float* __restrict__ bx1, const float* __restrict__ bh1,
    const float* __restrict__ hidden, const float* __restrict__ zbuf,
    u16* __restrict__ out_rh, float* __restrict__ out_zf,
    float* __restrict__ out_f) {
    constexpr int BM = 256, BK = 32, NKT = 64;       // K = 2048
    constexpr int WN = 1 << LWN, WM = 8 / WN;
    constexpr int PM = BM / WM, PN = BN / WN;        // (128,64) | (64,64)
    constexpr int FM = PM / 16, FN = PN / 16;        // (8,4) | (4,4)
    constexpr int AG = 2;                            // A dma instrs/thread/tile
    constexpr int BG = (BN * BK / 8) / 512;          // B reg loads/thread: 2 | 1

    __shared__ u16 As[4][BM * BK];                   // 64 KB
    __shared__ u16 Bs[4][BN * BK];                   // 64 | 32 KB

    const int tid = threadIdx.x;
    const int wave = tid >> 6;
    const int lane = tid & 63;
    // chunked XCD swizzle (nwg = 256 both modes, 8 bn-blocks both)
    const int wid = blockIdx.x;
    const int swz = (wid & 7) * 32 + (wid >> 3);
    const int bn = swz & 7;
    const int bm = swz >> 3;
    const int wc = wave & (WN - 1);
    const int wr = wave >> LWN;

    const floatx4 z4 = {0.f, 0.f, 0.f, 0.f};
    floatx4 acc[FM][FN];
#pragma unroll
    for (int i = 0; i < FM; ++i)
#pragma unroll
        for (int j = 0; j < FN; ++j) acc[i][j] = z4;

    // hoisted per-thread base pointers (inverse-swizzled coords; strides constexpr)
    const u16* aB0[AG];
    const u16* aB1[AG];
    const u16* bB[BG];
#pragma unroll
    for (int j = 0; j < AG; ++j) {
        const int c = j * 512 + tid;
        const int sup = c >> 3;
        const int u = (c & 7) ^ (sup & 7);
        const int r = sup * 2 + (u >> 2);
        const int k8 = (u & 3) * 8;
        aB0[j] = A0 + (size_t)(bm * BM + r) * SA0 + k8;
        aB1[j] = A1 + (size_t)(bm * BM + r) * SA1 + k8;
    }
#pragma unroll
    for (int j = 0; j < BG; ++j) {
        const int c = j * 512 + tid;
        const int sup = c >> 3;
        const int u = (c & 7) ^ (sup & 7);
        const int r = sup * 2 + (u >> 2);
        const int k8 = (u & 3) * 8;
        bB[j] = Bw + (size_t)(bn * BN + r) * 2048 + k8;
    }

    // swizzled ds_read bases (u16 idx): frag i at base + i*512
    const int mr = lane & 15;
    const int sg = lane >> 4;        // k-slot 0..3
    const int R0 = wr * PM + mr;
    const int baseA = (R0 >> 1) * 64 + (((((R0 & 1) << 2) | sg) ^ ((R0 >> 1) & 7)) << 3);
    const int C0 = wc * PN + mr;
    const int baseB = (C0 >> 1) * 64 + (((((C0 & 1) << 2) | sg) ^ ((C0 >> 1) & 7)) << 3);

    auto stageA = [&](int t) {       // DMA, buffer (t&3); ka advances by BK cols
        u16* Asb = &As[t & 3][0];
        const int ka = (t & (NKT / 2 - 1)) * BK;
        if (t < NKT / 2) {
#pragma unroll
            for (int j = 0; j < AG; ++j)
                g2l16(aB0[j] + ka, Asb + (j * 512 + wave * 64) * 8);
        } else {
#pragma unroll
            for (int j = 0; j < AG; ++j)
                g2l16(aB1[j] + ka, Asb + (j * 512 + wave * 64) * 8);
        }
    };

    bf16x8 pend[BG];                 // B in flight (static-indexed, rule #20)
    auto loadB = [&](int t) {
#pragma unroll
        for (int j = 0; j < BG; ++j)
            pend[j] = *(const bf16x8*)(bB[j] + t * BK);
    };
    auto writeB = [&](int t) {
#pragma unroll
        for (int j = 0; j < BG; ++j)
            *(bf16x8*)&Bs[t & 3][(size_t)(j * 512 + tid) * 8] = pend[j];
    };

    auto compute = [&](int t) {
        const u16* Asb = &As[t & 3][0];
        const u16* Bsb = &Bs[t & 3][0];
        bf16x8 af[FM], bv[FN];
#pragma unroll
        for (int i = 0; i < FM; ++i)
            af[i] = *(const bf16x8*)&Asb[baseA + i * 512];
#pragma unroll
        for (int j = 0; j < FN; ++j)
            bv[j] = *(const bf16x8*)&Bsb[baseB + j * 512];
        __builtin_amdgcn_s_setprio(1);
#pragma unroll
        for (int i = 0; i < FM; ++i)
#pragma unroll
            for (int j = 0; j < FN; ++j)
                acc[i][j] = __builtin_amdgcn_mfma_f32_16x16x32_bf16(
                    af[i], bv[j], acc[i][j], 0, 0, 0);
        __builtin_amdgcn_s_setprio(0);
    };

    // prologue: tiles 0..2 (B: load->wait->write; A: DMA); one full drain at end
#pragma unroll
    for (int p = 0; p < 3; ++p) {
        loadB(p);
        stageA(p);
        sbar0(); wait_vm2(); sbar0();   // pend(p) + A(p-1..) done; A(p) may fly
        writeB(p);
    }
    sbar0(); wait_vm0();
    __syncthreads();                    // A(0..2) + all B writes visible

    // steady: issue B(t+3)+A(t+3); compute(t); vmcnt(2) [pend ready, A(t+1) done];
    // write B(t+3); barrier.  Buffer (t+3)&3 was freed by barrier ending t-1.
    for (int t = 0; t < NKT - 3; ++t) {   // 0..60
        loadB(t + 3);
        stageA(t + 3);
        compute(t);
        sbar0(); wait_vm2(); sbar0();
        writeB(t + 3);
        sbar0();
        __builtin_amdgcn_s_barrier();
        sbar0();
    }
    // tail: everything staged; A(61),A(62),B(*) complete per t=60's vmcnt(2)
    compute(NKT - 3);
    compute(NKT - 2);
    sbar0(); wait_vm0();                  // A(63) DMA done (per-wave) ...
    __builtin_amdgcn_s_barrier();         // ... and across all waves
    sbar0();
    compute(NKT - 1);

    // epilogue: C/D layout col=lane&15, row=(lane>>4)*4+reg (m89/m91 verified)
    const int colBase = bn * BN + wc * PN + (lane & 15);
    const int rowBase = bm * BM + wr * PM + (lane >> 4) * 4;
    if constexpr (MODE == 0) {
        const bool is_r = (colBase < H_SZ);   // block-uniform (1024 % BN == 0)
#pragma unroll
        for (int j = 0; j < FN; ++j) {
            const int coln = colBase + j * 16;
            const int cb = is_r ? coln : coln - H_SZ;
            const float bias = is_r ? (bx0[cb] + bh0[cb]) : (bx1[cb] + bh1[cb]);
#pragma unroll
            for (int i = 0; i < FM; ++i) {
#pragma unroll
                for (int r = 0; r < 4; ++r) {
                    const int rown = rowBase + i * 16 + r;
                    const size_t idx = (size_t)rown * H_SZ + cb;
                    const float v = acc[i][j][r] + bias;
                    const float s = 1.0f / (1.0f + __expf(-v));
                    if (is_r) out_rh[idx] = f2bf(s * hidden[idx]);
                    else      out_zf[idx] = s;
                }
            }
        }
    } else {
#pragma unroll
        for (int j = 0; j < FN; ++j) {
            const int coln = colBase + j * 16;
            const float bias = bx0[coln] + bh0[coln];
#pragma unroll
            for (int i = 0; i < FM; ++i) {
#pragma unroll
                for (int r = 0; r < 4; ++r) {
                    const int rown = rowBase + i * 16 + r;
                    const size_t idx = (size_t)rown * H_SZ + coln;
                    const float v = acc[i][j][r] + bias;
                    const float ht = tanhf(v);
                    const float zz = zbuf[idx];
                    const float hh = hidden[idx];
                    out_f[idx] = zz * hh + (1.0f - zz) * ht;
                }
            }
        }
    }
}

// distinct kernel names so rocprof separates the two GEMMs
__global__ __launch_bounds__(512) void gemm_rz(
    const u16* __restrict__ A0, const u16* __restrict__ A1,
    const u16* __restrict__ Bw,
    const float* __restrict__ bx0, const float* __restrict__ bh0,
    const float* __restrict__ bx1, const float* __restrict__ bh1,
    const float* __restrict__ hidden,
    u16* __restrict__ out_rh, float* __restrict__ out_zf) {
    gemm_core<0, 256, 2, 2048, 2048>(A0, A1, Bw, bx0, bh0, bx1, bh1,
                                     hidden, nullptr, out_rh, out_zf, nullptr);
}

__global__ __launch_bounds__(512) void gemm_h(
    const u16* __restrict__ A0, const u16* __restrict__ A1,
    const u16* __restrict__ Bw,
    const float* __restrict__ bx0, const float* __restrict__ bh0,
    const float* __restrict__ hidden, const float* __restrict__ zbuf,
    float* __restrict__ out_f) {
    gemm_core<2, 128, 1, 2048, 1024>(A0, A1, Bw, bx0, bh0, nullptr, nullptr,
                                     hidden, zbuf, nullptr, nullptr, out_f);
}

// ---------------- row-wise log_softmax over H=1024 ----------------
__global__ __launch_bounds__(256) void lsm_kernel(const float* __restrict__ nh,
                                                  float* __restrict__ out) {
    const int row = blockIdx.x;
    const int tid = threadIdx.x;
    const int wave = tid >> 6, lane = tid & 63;
    const float4 v = ((const float4*)(nh + (size_t)row * H_SZ))[tid];
    __shared__ float redm[4];
    __shared__ float reds[4];
    float m = fmaxf(fmaxf(v.x, v.y), fmaxf(v.z, v.w));
#pragma unroll
    for (int o = 32; o; o >>= 1) m = fmaxf(m, __shfl_xor(m, o));
    if (lane == 0) redm[wave] = m;
    __syncthreads();
    const float M = fmaxf(fmaxf(redm[0], redm[1]), fmaxf(redm[2], redm[3]));
    float s = __expf(v.x - M) + __expf(v.y - M) + __expf(v.z - M) + __expf(v.w - M);
#pragma unroll
    for (int o = 32; o; o >>= 1) s += __shfl_xor(s, o);
    if (lane == 0) reds[wave] = s;
    __syncthreads();
    const float S = reds[0] + reds[1] + reds[2] + reds[3];
    const float lse = M + __logf(S);
    float4 ov;
    ov.x = v.x - lse; ov.y = v.y - lse; ov.z = v.z - lse; ov.w = v.w - lse;
    ((float4*)(out + (size_t)row * H_SZ))[tid] = ov;
}

extern "C" void kernel_launch(void* const* d_in, const int* in_sizes, int n_in,
                              void* d_out, int out_size, void* d_ws, size_t ws_size,
                              hipStream_t stream) {
    const float* input  = (const float*)d_in[0];
    const float* hidden = (const float*)d_in[1];
    const float* Wir = (const float*)d_in[2];  const float* bir = (const float*)d_in[3];
    const float* Whr = (const float*)d_in[4];  const float* bhr = (const float*)d_in[5];
    const float* Wiz = (const float*)d_in[6];  const float* biz = (const float*)d_in[7];
    const float* Whz = (const float*)d_in[8];  const float* bhz = (const float*)d_in[9];
    const float* Wih = (const float*)d_in[10]; const float* bih = (const float*)d_in[11];
    const float* Whh = (const float*)d_in[12]; const float* bhh = (const float*)d_in[13];

    // workspace layout (92 MB total)
    char* ws = (char*)d_ws;
    u16* Acat = (u16*)(ws);                     // 32 MB  [8192][2048] = [X | H]
    u16* Brz  = (u16*)(ws + (32u << 20));       //  8 MB  [2048][2048]
    u16* Bh   = (u16*)(ws + (40u << 20));       //  4 MB  [1024][2048]
    u16* RHb  = (u16*)(ws + (44u << 20));       // 16 MB  [8192][1024] r*hidden bf16
    float* Zf = (float*)(ws + (60u << 20));     // 32 MB  z f32

    float* out_lsm = (float*)d_out;
    float* out_nh  = (float*)d_out + (size_t)B_SZ * H_SZ;

    cvt_all<<<22528, 256, 0, stream>>>(
        input, hidden, Wir, Whr, Wiz, Whz, Wih, Whh, Acat, Brz, Bh);

    // fused r+z GEMM: M=8192 N=2048 K=2048, 256x256 tiles -> 256 blocks
    gemm_rz<<<256, 512, 0, stream>>>(
        Acat, Acat + 1024, Brz, bir, bhr, biz, bhz, hidden, RHb, Zf);
    // h~ GEMM: M=8192 N=1024 K=2048 (X | RHb), 256x128 tiles -> 256 blocks
    gemm_h<<<256, 512, 0, stream>>>(
        Acat, RHb, Bh, bih, bhh, hidden, Zf, out_nh);

    lsm_kernel<<<B_SZ, 256, 0, stream>>>(out_nh, out_lsm);
}